// Round 8
// baseline (39.274 us; speedup 1.0000x reference)
//
#include <hip/hip_runtime.h>

// ROI max-pool, single kernel. feature_map: (1,256,50,50) f32,
// bboxes: (512,4) f32, out: (512,256,7,7) f32, scale=1/16, pooled=7.
//
// One 512-thread block per box. For each h-row of the ROI:
//   stage:   all 8 waves copy row h (256 c x ROI width) NCHW -> LDS
//            rowbuf[w][c] (PAD=260 keeps rows 16B-aligned), coalesced
//            w-fastest global reads.
//   compute: wave q (=bin column, q<7) reads channel-contiguous float4
//            (64 lanes x 16B = contiguous 1KB -> conflict-free b128)
//            and updates m[p] for all p-bins containing h.
// Then results staged to LDS in final (c,p,q) layout and written out as
// coalesced float4s. No workspace, no second kernel.

#define CC   256
#define HH   50
#define WW   50
#define NBOX 512
#define PP   7
#define SCL  (1.0f / 16.0f)
#define HW   (HH * WW)             // 2500
#define OUT_PER_BOX (CC * PP * PP) // 12544
#define PAD  260                   // words per w-row: 16B-aligned (260*4 % 16 == 0)

__global__ __launch_bounds__(512) void roipool_strip_kernel(
    const float* __restrict__ feat,
    const float* __restrict__ boxes,
    float* __restrict__ out)
{
    __shared__ float smem[WW * PAD];   // 13000 f32 = 52000 B; reused for out-staging
    int n    = blockIdx.x;
    int tid  = threadIdx.x;
    int wave = tid >> 6;               // 0..7 ; waves 0..6 = bin column q
    int lane = tid & 63;               // channel quad: c = 4*lane..4*lane+3

    const float* b = boxes + n * 4;
    int x1 = (int)floorf(b[0] * SCL + 0.5f);
    int y1 = (int)floorf(b[1] * SCL + 0.5f);
    int x2 = (int)floorf(b[2] * SCL + 0.5f);
    int y2 = (int)floorf(b[3] * SCL + 0.5f);
    int rw = max(x2 - x1 + 1, 1);
    int rh = max(y2 - y1 + 1, 1);

    // union of all bin ranges = [x1, x1+rw) x [y1, y1+rh), clipped to feature
    int wlo = min(max(x1, 0), WW);
    int whi = min(max(x1 + rw, 0), WW);
    int hlo = min(max(y1, 0), HH);
    int hhi = min(max(y1 + rh, 0), HH);
    int rwc = whi - wlo;               // >=1 for valid boxes (x1 <= 38)

    // per-wave bin-column bounds (wave-uniform)
    int q = wave;
    int wsq = 0, weq = 0;
    if (q < PP) {
        wsq = min(max(q * rw / PP + x1, 0), WW);
        weq = min(max(((q + 1) * rw + PP - 1) / PP + x1, 0), WW);
    }

    // per-bin h bounds, kept in registers via full unroll
    int hs[PP], he[PP];
    #pragma unroll
    for (int p = 0; p < PP; ++p) {
        hs[p] = min(max(p * rh / PP + y1, 0), HH);
        he[p] = min(max(((p + 1) * rh + PP - 1) / PP + y1, 0), HH);
    }

    float4 m[PP];
    #pragma unroll
    for (int p = 0; p < PP; ++p)
        m[p] = make_float4(-INFINITY, -INFINITY, -INFINITY, -INFINITY);

    // staging decomposition of i = tid + k*512 -> (w = i % rwc, c = i / rwc),
    // computed once (one runtime divmod) then carried with cheap increments
    int w0 = tid % rwc, c0 = tid / rwc;
    int dw = 512 % rwc, dc = 512 / rwc;

    for (int h = hlo; h < hhi; ++h) {
        // ---- stage row h (all 512 threads): rowbuf[w][c] = feat[c][h][wlo+w]
        {
            const float* src = feat + h * WW + wlo;
            int w = w0, c = c0;
            while (c < CC) {
                smem[w * PAD + c] = src[c * HW + w];  // global: coalesced w-fast
                w += dw; c += dc;
                if (w >= rwc) { w -= rwc; ++c; }
            }
        }
        __syncthreads();
        // ---- compute (waves 0..6): contiguous 1KB b128 reads, conflict-free
        if (q < PP) {
            #pragma unroll
            for (int p = 0; p < PP; ++p) {
                if (h >= hs[p] && h < he[p]) {
                    for (int w = wsq; w < weq; ++w) {
                        const float4 v =
                            *(const float4*)&smem[(w - wlo) * PAD + 4 * lane];
                        m[p].x = fmaxf(m[p].x, v.x);
                        m[p].y = fmaxf(m[p].y, v.y);
                        m[p].z = fmaxf(m[p].z, v.z);
                        m[p].w = fmaxf(m[p].w, v.w);
                    }
                }
            }
        }
        __syncthreads();
    }

    // ---- stage results in final layout: smem[c*49 + p*7 + q]
    if (q < PP) {
        #pragma unroll
        for (int p = 0; p < PP; ++p) {
            bool empty = (he[p] <= hs[p]) || (weq <= wsq);
            float4 v = empty ? make_float4(0.f, 0.f, 0.f, 0.f) : m[p];
            int base = (4 * lane) * 49 + p * PP + q;
            smem[base      ] = v.x;
            smem[base +  49] = v.y;
            smem[base +  98] = v.z;
            smem[base + 147] = v.w;
        }
    }
    __syncthreads();

    // ---- coalesced float4 writeback of the whole box
    const float4* s4 = (const float4*)smem;
    float4*       o4 = (float4*)(out + n * OUT_PER_BOX);
    for (int i = tid; i < OUT_PER_BOX / 4; i += 512)   // 3136 float4s
        o4[i] = s4[i];
}

extern "C" void kernel_launch(void* const* d_in, const int* in_sizes, int n_in,
                              void* d_out, int out_size, void* d_ws, size_t ws_size,
                              hipStream_t stream)
{
    const float* feat  = (const float*)d_in[0];
    const float* boxes = (const float*)d_in[1];
    float* out = (float*)d_out;

    roipool_strip_kernel<<<NBOX, 512, 0, stream>>>(feat, boxes, out);
}

// Round 9
// 25.221 us; speedup vs baseline: 1.5572x; 1.5572x over previous
//
#include <hip/hip_runtime.h>

// ROI max-pool. feature_map: (1,256,50,50) f32, bboxes: (512,4) f32,
// out: (512,256,7,7) f32, scale = 1/16, pooled = 7.
//
// Kernel 1: gather-transpose NCHW -> NHWC into d_ws. One thread per
//           (hw, channel-quad): 4 scalar reads (stride HW, L2-absorbed,
//           ~41 MB L2 traffic) + 1 coalesced float4 write (1 KB/wave).
//           625 blocks x 256 thr -> all CUs busy, no LDS, no barrier.
// Kernel 2: one 1024-thread block per box (2 blocks/CU = 32 waves/CU);
//           wave-uniform bin loops; lane l float4-loads channels 4l..4l+3
//           from featT; LDS staged in final layout; coalesced writeback.

#define CC   256
#define HH   50
#define WW   50
#define NBOX 512
#define PP   7
#define SCL  (1.0f / 16.0f)
#define HW   (HH * WW)             // 2500
#define OUT_PER_BOX (CC * PP * PP) // 12544
#define NBIN (PP * PP)             // 49

// ---------- Kernel 1: (C, HW) -> (HW, C) gather transpose ---------------
__global__ __launch_bounds__(256) void transpose_kernel(
    const float* __restrict__ feat, float* __restrict__ featT)
{
    int gid = blockIdx.x * 256 + threadIdx.x;   // 0 .. 160000 (= HW * 64)
    int cq  = gid & 63;                         // channel quad index
    int hw  = gid >> 6;                         // spatial position
    const float* s = feat + 4 * cq * HW + hw;
    float4 v;
    v.x = s[0 * HW];
    v.y = s[1 * HW];
    v.z = s[2 * HW];
    v.w = s[3 * HW];
    ((float4*)featT)[gid] = v;                  // lanes -> contiguous 1 KB
}

// ---------- Kernel 2: one 1024-thread block per box ----------------------
__global__ __launch_bounds__(1024, 8) void pool_kernel(
    const float* __restrict__ featT,
    const float* __restrict__ boxes,
    float* __restrict__ out)
{
    __shared__ float smem[OUT_PER_BOX];     // 50176 B, FINAL layout: c*49+pq
    int n    = blockIdx.x;
    int tid  = threadIdx.x;
    int wave = tid >> 6;                    // 0..15
    int lane = tid & 63;

    const float* b = boxes + n * 4;
    int x1 = (int)floorf(b[0] * SCL + 0.5f);
    int y1 = (int)floorf(b[1] * SCL + 0.5f);
    int x2 = (int)floorf(b[2] * SCL + 0.5f);
    int y2 = (int)floorf(b[3] * SCL + 0.5f);
    int rw = max(x2 - x1 + 1, 1);
    int rh = max(y2 - y1 + 1, 1);

    const float* fl = featT + 4 * lane;     // lane's channel quad base

    // wave w handles bins pq = w, w+16, w+32 : bounds are wave-uniform
    for (int pq = wave; pq < NBIN; pq += 16) {
        int p = pq / PP, q = pq % PP;
        int hs = min(max(p * rh / PP + y1, 0), HH);
        int he = min(max(((p + 1) * rh + PP - 1) / PP + y1, 0), HH);
        int ws = min(max(q * rw / PP + x1, 0), WW);
        int we = min(max(((q + 1) * rw + PP - 1) / PP + x1, 0), WW);

        float4 m = make_float4(-INFINITY, -INFINITY, -INFINITY, -INFINITY);
        for (int h = hs; h < he; ++h) {
            const float* base = fl + h * (WW * CC);
            for (int w = ws; w < we; ++w) {
                float4 v = *(const float4*)(base + w * CC);  // 1 KB/wave-load
                m.x = fmaxf(m.x, v.x);
                m.y = fmaxf(m.y, v.y);
                m.z = fmaxf(m.z, v.z);
                m.w = fmaxf(m.w, v.w);
            }
        }
        if ((he <= hs) || (we <= ws))
            m = make_float4(0.0f, 0.0f, 0.0f, 0.0f);

        // final layout: smem[(4l+j)*49 + pq]; small store conflicts traded
        // for a pure-vector coalesced writeback below
        int base = (4 * lane) * 49 + pq;
        smem[base      ] = m.x;
        smem[base +  49] = m.y;
        smem[base +  98] = m.z;
        smem[base + 147] = m.w;
    }
    __syncthreads();

    // pure float4 copy: LDS already in output order, fully coalesced stores
    const float4* s4 = (const float4*)smem;
    float4*       o4 = (float4*)(out + n * OUT_PER_BOX);
    for (int i = tid; i < OUT_PER_BOX / 4; i += 1024)   // 3136 float4s
        o4[i] = s4[i];
}

extern "C" void kernel_launch(void* const* d_in, const int* in_sizes, int n_in,
                              void* d_out, int out_size, void* d_ws, size_t ws_size,
                              hipStream_t stream)
{
    const float* feat  = (const float*)d_in[0];
    const float* boxes = (const float*)d_in[1];
    float* out = (float*)d_out;

    float* featT = (float*)d_ws;            // 2,560,000 B needed
    transpose_kernel<<<(HW * 64) / 256, 256, 0, stream>>>(feat, featT);
    pool_kernel<<<NBOX, 1024, 0, stream>>>(featT, boxes, out);
}

// Round 11
// 21.928 us; speedup vs baseline: 1.7911x; 1.1502x over previous
//
#include <hip/hip_runtime.h>

// ROI max-pool. feature_map: (1,256,50,50) f32, bboxes: (512,4) f32,
// out: (512,256,7,7) f32, scale = 1/16, pooled = 7.
//
// Kernel 1 (best measured, R5): NCHW -> NHWC transpose via 64x64 LDS tiles.
// Kernel 2: one 1024-thread block per box (2 blocks/CU = 32 waves/CU);
//           wave-uniform bin loops; lane l float4-loads channels 4l..4l+3;
//           LDS staged in final layout; NONTEMPORAL coalesced writeback
//           (output is a 25.7 MB stream, never re-read -> don't pollute L2).

#define CC   256
#define HH   50
#define WW   50
#define NBOX 512
#define PP   7
#define SCL  (1.0f / 16.0f)
#define HW   (HH * WW)             // 2500
#define OUT_PER_BOX (CC * PP * PP) // 12544
#define NBIN (PP * PP)             // 49

typedef float f32x4 __attribute__((ext_vector_type(4)));  // native vec for nt-store

// ---------- Kernel 1: (C, HW) -> (HW, C) transpose via 64x64 LDS tiles ----
__global__ __launch_bounds__(256) void transpose_kernel(
    const float* __restrict__ feat, float* __restrict__ featT)
{
    __shared__ float tile[64][65];          // +1 pad -> conflict-free column reads
    int tc = blockIdx.x & 3;                // channel tile 0..3
    int th = blockIdx.x >> 2;               // hw tile 0..39
    int c0 = tc * 64, h0 = th * 64;
    int lane = threadIdx.x & 63;
    int row4 = threadIdx.x >> 6;            // 0..3

    for (int it = 0; it < 16; ++it) {
        int r  = row4 + it * 4;             // c-row in tile
        int hw = h0 + lane;
        if (hw < HW)
            tile[r][lane] = feat[(c0 + r) * HW + hw];   // coalesced along hw
    }
    __syncthreads();
    for (int it = 0; it < 16; ++it) {
        int r  = row4 + it * 4;             // hw-row in tile
        int hw = h0 + r;
        if (hw < HW)
            featT[hw * CC + c0 + lane] = tile[lane][r]; // coalesced along c
    }
}

// ---------- Kernel 2: one 1024-thread block per box ----------------------
__global__ __launch_bounds__(1024, 8) void pool_kernel(
    const float* __restrict__ featT,
    const float* __restrict__ boxes,
    float* __restrict__ out)
{
    __shared__ float smem[OUT_PER_BOX];     // 50176 B, FINAL layout: c*49+pq
    int n    = blockIdx.x;
    int tid  = threadIdx.x;
    int wave = tid >> 6;                    // 0..15
    int lane = tid & 63;

    const float* b = boxes + n * 4;
    int x1 = (int)floorf(b[0] * SCL + 0.5f);
    int y1 = (int)floorf(b[1] * SCL + 0.5f);
    int x2 = (int)floorf(b[2] * SCL + 0.5f);
    int y2 = (int)floorf(b[3] * SCL + 0.5f);
    int rw = max(x2 - x1 + 1, 1);
    int rh = max(y2 - y1 + 1, 1);

    const float* fl = featT + 4 * lane;     // lane's channel quad base

    // wave w handles bins pq = w, w+16, w+32 : bounds are wave-uniform
    for (int pq = wave; pq < NBIN; pq += 16) {
        int p = pq / PP, q = pq % PP;
        int hs = min(max(p * rh / PP + y1, 0), HH);
        int he = min(max(((p + 1) * rh + PP - 1) / PP + y1, 0), HH);
        int ws = min(max(q * rw / PP + x1, 0), WW);
        int we = min(max(((q + 1) * rw + PP - 1) / PP + x1, 0), WW);

        float4 m = make_float4(-INFINITY, -INFINITY, -INFINITY, -INFINITY);
        for (int h = hs; h < he; ++h) {
            const float* base = fl + h * (WW * CC);
            for (int w = ws; w < we; ++w) {
                float4 v = *(const float4*)(base + w * CC);  // 1 KB/wave-load
                m.x = fmaxf(m.x, v.x);
                m.y = fmaxf(m.y, v.y);
                m.z = fmaxf(m.z, v.z);
                m.w = fmaxf(m.w, v.w);
            }
        }
        if ((he <= hs) || (we <= ws))
            m = make_float4(0.0f, 0.0f, 0.0f, 0.0f);

        // final layout: smem[(4l+j)*49 + pq]; small store conflicts traded
        // for a pure-vector coalesced writeback below
        int base = (4 * lane) * 49 + pq;
        smem[base      ] = m.x;
        smem[base +  49] = m.y;
        smem[base +  98] = m.z;
        smem[base + 147] = m.w;
    }
    __syncthreads();

    // pure vector copy: LDS already in output order; nontemporal stores
    // keep the 25.7 MB output stream from evicting featT in L2
    const f32x4* s4 = (const f32x4*)smem;
    f32x4*       o4 = (f32x4*)(out + n * OUT_PER_BOX);
    for (int i = tid; i < OUT_PER_BOX / 4; i += 1024) { // 3136 vec4s
        f32x4 v = s4[i];
        __builtin_nontemporal_store(v, o4 + i);
    }
}

extern "C" void kernel_launch(void* const* d_in, const int* in_sizes, int n_in,
                              void* d_out, int out_size, void* d_ws, size_t ws_size,
                              hipStream_t stream)
{
    const float* feat  = (const float*)d_in[0];
    const float* boxes = (const float*)d_in[1];
    float* out = (float*)d_out;

    float* featT = (float*)d_ws;            // 2,560,000 B needed
    transpose_kernel<<<40 * 4, 256, 0, stream>>>(feat, featT);
    pool_kernel<<<NBOX, 1024, 0, stream>>>(featT, boxes, out);
}